// Round 1
// baseline (2032.048 us; speedup 1.0000x reference)
//
#include <hip/hip_runtime.h>
#include <hip/hip_bf16.h>

#define E_TOT   10000
#define CI      16
#define CO      16
#define FREQ    44
#define IN_DIM  16
#define OUT_DIM 16
#define EDGE_F  16
#define MID     32
#define CK      704      // CI*FREQ
#define NCK     11264    // CO*CK
#define LN_EPS  1e-5f

// ---------------- K1: RadialProfile MLP (fp32 exact), one thread per edge ----
__global__ void k_mlp(const float* __restrict__ inv,
                      const float* __restrict__ w1, const float* __restrict__ b1,
                      const float* __restrict__ g1, const float* __restrict__ be1,
                      const float* __restrict__ w2, const float* __restrict__ b2,
                      const float* __restrict__ g2, const float* __restrict__ be2,
                      float* __restrict__ h_out) {
  int e = blockIdx.x * blockDim.x + threadIdx.x;
  if (e >= E_TOT) return;
  float x[EDGE_F];
#pragma unroll
  for (int i = 0; i < EDGE_F; ++i) x[i] = inv[(size_t)e * EDGE_F + i];

  float a[MID];
  float m = 0.f;
#pragma unroll
  for (int j = 0; j < MID; ++j) {
    float s = b1[j];
#pragma unroll
    for (int i = 0; i < EDGE_F; ++i) s = fmaf(x[i], w1[j * EDGE_F + i], s);
    a[j] = s; m += s;
  }
  m *= (1.f / MID);
  float v = 0.f;
#pragma unroll
  for (int j = 0; j < MID; ++j) { float d = a[j] - m; v = fmaf(d, d, v); }
  v *= (1.f / MID);
  float r = rsqrtf(v + LN_EPS);
#pragma unroll
  for (int j = 0; j < MID; ++j)
    a[j] = fmaxf(fmaf((a[j] - m) * r, g1[j], be1[j]), 0.f);

  float c[MID];
  m = 0.f;
#pragma unroll
  for (int j = 0; j < MID; ++j) {
    float s = b2[j];
#pragma unroll
    for (int k = 0; k < MID; ++k) s = fmaf(a[k], w2[j * MID + k], s);
    c[j] = s; m += s;
  }
  m *= (1.f / MID);
  v = 0.f;
#pragma unroll
  for (int j = 0; j < MID; ++j) { float d = c[j] - m; v = fmaf(d, d, v); }
  v *= (1.f / MID);
  r = rsqrtf(v + LN_EPS);
#pragma unroll
  for (int j = 0; j < MID; ++j) {
    float y = fmaxf(fmaf((c[j] - m) * r, g2[j], be2[j]), 0.f);
    h_out[(size_t)e * MID + j] = y;
  }
}

// ---------------- K2: rw[e][ck] = h[e] . w3[ck]  (bf16 out), 64 edges x 256 ck per block
__global__ void k_rw(const float* __restrict__ h, const float* __restrict__ w3,
                     __hip_bfloat16* __restrict__ rw, int e0, int e1) {
  __shared__ float hs[64][MID];
  const int t = threadIdx.x;
  const int ebase = e0 + blockIdx.y * 64;
#pragma unroll
  for (int r = 0; r < 8; ++r) {
    int idx = r * 256 + t;
    int er = ebase + (idx >> 5);
    if (er < e1) hs[idx >> 5][idx & 31] = h[(size_t)er * MID + (idx & 31)];
  }
  __syncthreads();
  const int ck = blockIdx.x * 256 + t;
  float4 w[8];
  const float4* wv = (const float4*)(w3 + (size_t)ck * MID);
#pragma unroll
  for (int q = 0; q < 8; ++q) w[q] = wv[q];
  const int ne = min(64, e1 - ebase);
  for (int ep = 0; ep < ne; ++ep) {
    const float4* hv = (const float4*)hs[ep];
    float s = 0.f;
#pragma unroll
    for (int q = 0; q < 8; ++q) {
      float4 aa = hv[q]; float4 bb = w[q];
      s = fmaf(aa.x, bb.x, s); s = fmaf(aa.y, bb.y, s);
      s = fmaf(aa.z, bb.z, s); s = fmaf(aa.w, bb.w, s);
    }
    rw[(size_t)(ebase - e0 + ep) * NCK + ck] = __float2bfloat16(s);
  }
}

// ---------------- K3: fused  tmp = feat @ basis_row ; out = rw @ tmp ---------
// one block per edge, 256 threads
__global__ void k_out(const float* __restrict__ feat,
                      const float* __restrict__ basis,
                      const __hip_bfloat16* __restrict__ rw,
                      float* __restrict__ out, int e0) {
  __shared__ float tmpT[16][708];   // [o][k], padded 704->708 to break bank conflicts
  __shared__ float feats[256];      // [ci*16+i]
  const int t = threadIdx.x;
  const int eloc = blockIdx.x;
  const int e = e0 + eloc;

  feats[t] = feat[(size_t)e * 256 + t];
  __syncthreads();

  const float* basrow = basis + (size_t)e * NCK;  // [i][f*16+o] = [i][fo], 16x704
  float acc[16][3];
#pragma unroll
  for (int ci = 0; ci < 16; ++ci) { acc[ci][0] = acc[ci][1] = acc[ci][2] = 0.f; }
  const bool has2 = (t < 192);
#pragma unroll
  for (int i = 0; i < 16; ++i) {
    float bv0 = basrow[i * 704 + t];
    float bv1 = basrow[i * 704 + 256 + t];
    float bv2 = has2 ? basrow[i * 704 + 512 + t] : 0.f;
#pragma unroll
    for (int ci = 0; ci < 16; ++ci) {
      float f = feats[ci * 16 + i];
      acc[ci][0] = fmaf(f, bv0, acc[ci][0]);
      acc[ci][1] = fmaf(f, bv1, acc[ci][1]);
      acc[ci][2] = fmaf(f, bv2, acc[ci][2]);
    }
  }
  // scatter tmp[ci][fo] -> tmpT[o][ci*44 + f]   (fo = f*16+o)
  {
    const int o0 = t & 15,          f0 = t >> 4;
    const int fo1 = 256 + t; const int o1 = fo1 & 15, f1 = fo1 >> 4;
    const int fo2 = 512 + t; const int o2 = fo2 & 15, f2 = fo2 >> 4;
#pragma unroll
    for (int ci = 0; ci < 16; ++ci) {
      tmpT[o0][ci * 44 + f0] = acc[ci][0];
      tmpT[o1][ci * 44 + f1] = acc[ci][1];
      if (has2) tmpT[o2][ci * 44 + f2] = acc[ci][2];
    }
  }
  __syncthreads();

  // out[co][o] = sum_k rw[co*704+k] * tmpT[o][k]
  const int co = t >> 4, o = t & 15;
  const unsigned int* rwu = (const unsigned int*)(rw + (size_t)eloc * NCK);
  float s = 0.f;
#pragma unroll 4
  for (int k4 = 0; k4 < 176; ++k4) {
    uint2 rr = *(const uint2*)(rwu + co * 352 + k4 * 2);
    float4 tv = *(const float4*)&tmpT[o][k4 * 4];
    float f0 = __uint_as_float(rr.x << 16);
    float f1 = __uint_as_float(rr.x & 0xffff0000u);
    float f2 = __uint_as_float(rr.y << 16);
    float f3 = __uint_as_float(rr.y & 0xffff0000u);
    s = fmaf(f0, tv.x, s); s = fmaf(f1, tv.y, s);
    s = fmaf(f2, tv.z, s); s = fmaf(f3, tv.w, s);
  }
  out[(size_t)e * 256 + t] = s;
}

extern "C" void kernel_launch(void* const* d_in, const int* in_sizes, int n_in,
                              void* d_out, int out_size, void* d_ws, size_t ws_size,
                              hipStream_t stream) {
  const float* feat  = (const float*)d_in[0];
  const float* inv   = (const float*)d_in[1];
  const float* basis = (const float*)d_in[2];
  const float* w1  = (const float*)d_in[3];
  const float* b1  = (const float*)d_in[4];
  const float* g1  = (const float*)d_in[5];
  const float* be1 = (const float*)d_in[6];
  const float* w2  = (const float*)d_in[7];
  const float* b2  = (const float*)d_in[8];
  const float* g2  = (const float*)d_in[9];
  const float* be2 = (const float*)d_in[10];
  const float* w3  = (const float*)d_in[11];
  float* out = (float*)d_out;

  float* h = (float*)d_ws;
  size_t h_bytes = (size_t)E_TOT * MID * sizeof(float);
  __hip_bfloat16* rwbuf = (__hip_bfloat16*)((char*)d_ws + h_bytes);
  size_t per_edge = (size_t)NCK * sizeof(__hip_bfloat16);
  size_t avail = ws_size > h_bytes ? ws_size - h_bytes : 0;
  long long chunkE = (long long)(avail / per_edge);
  if (chunkE > E_TOT) chunkE = E_TOT;
  if (chunkE < 1) chunkE = 1;  // (assumes ws_size is at least ~23 KB + h)

  k_mlp<<<(E_TOT + 255) / 256, 256, 0, stream>>>(inv, w1, b1, g1, be1,
                                                 w2, b2, g2, be2, h);
  for (int e0 = 0; e0 < E_TOT; e0 += (int)chunkE) {
    int ec = min((int)chunkE, E_TOT - e0);
    dim3 grw(NCK / 256, (ec + 63) / 64);
    k_rw<<<grw, 256, 0, stream>>>(h, w3, rwbuf, e0, e0 + ec);
    k_out<<<ec, 256, 0, stream>>>(feat, basis, rwbuf, out, e0);
  }
}